// Round 4
// baseline (373.235 us; speedup 1.0000x reference)
//
#include <hip/hip_runtime.h>

typedef unsigned short u16;
typedef short short8 __attribute__((ext_vector_type(8)));
typedef short short4v __attribute__((ext_vector_type(4)));
typedef float f32x4 __attribute__((ext_vector_type(4)));
typedef float f4 __attribute__((ext_vector_type(4)));

#define MFMA16(a, b, c) __builtin_amdgcn_mfma_f32_16x16x32_bf16(a, b, c, 0, 0, 0)
// K=16 variant: B-fragment layout == C/D layout -> chain MFMAs in registers
#define MFMA1K(a, b, c) __builtin_amdgcn_mfma_f32_16x16x16bf16_1k(a, b, c, 0, 0, 0)

__device__ inline u16 f2bf(float f) {
    unsigned int v = __builtin_bit_cast(unsigned int, f);
    unsigned int r = (v + 0x7FFFu + ((v >> 16) & 1u)) >> 16;
    return (u16)r;
}
__device__ inline short4v pack4(f4 v) {
    short4v r;
#pragma unroll
    for (int j = 0; j < 4; ++j) r[j] = (short)f2bf(v[j]);
    return r;
}

// ---------------------------------------------------------------------------
// Kernel 0: one-time weight prep. Transpose Wsr (per tap), Wq, Wp to bf16
// [co][ci] row-major in ws. Grid 66: bid<64 = tap, 64 = Wq, 65 = Wp.
// ---------------------------------------------------------------------------
__global__ __launch_bounds__(256) void prep_kernel(
    const float* __restrict__ Wsr, const float* __restrict__ Wq,
    const float* __restrict__ Wp,
    u16* __restrict__ WsrT, u16* __restrict__ WqT, u16* __restrict__ WpT)
{
    const int bid = blockIdx.x;
    const int tid = threadIdx.x;
    __shared__ float sT[64 * 65];
    const float* src;
    u16* dst;
    if (bid < 64)      { src = Wsr + (size_t)bid * 4096; dst = WsrT + (size_t)bid * 4096; }
    else if (bid == 64){ src = Wq;  dst = WqT; }
    else               { src = Wp;  dst = WpT; }
#pragma unroll
    for (int p = 0; p < 4; ++p) {
        int idx = p * 256 + tid;
        int r = idx >> 4, c4 = (idx & 15) * 4;
        f4 v = *(const f4*)(src + r * 64 + c4);
#pragma unroll
        for (int j = 0; j < 4; ++j) sT[r * 65 + c4 + j] = v[j];
    }
    __syncthreads();
#pragma unroll
    for (int p = 0; p < 2; ++p) {
        int idx = p * 256 + tid;
        int co = idx >> 3, g = (idx & 7) * 8;
        short8 o;
#pragma unroll
        for (int j = 0; j < 8; ++j) o[j] = (short)f2bf(sT[(g + j) * 65 + co]);
        *(short8*)(dst + (size_t)co * 64 + g) = o;
    }
}

// ---------------------------------------------------------------------------
// Kernel 1: split-K conv partials. Grid 512 = 16 ksplits x 32 mtiles
// (2 blocks/CU for latency hiding, 4 serial taps each).
// fp32 partials [16][2048][64].  (Round-0 proven LDS-staged version.)
// ---------------------------------------------------------------------------
__global__ __launch_bounds__(256) void conv_partial_kernel(
    const float* __restrict__ x, const u16* __restrict__ WsrT,
    float* __restrict__ partials)
{
    const int mtile  = blockIdx.x & 31;
    const int ksplit = blockIdx.x >> 5;
    const int tid  = threadIdx.x;
    const int wave = tid >> 6;
    const int lane = tid & 63;
    const int l15  = lane & 15;
    const int quad = lane >> 4;

    __shared__ u16 sA[64 * 72];
    __shared__ u16 sB[64 * 72];

    f32x4 acc[4];
#pragma unroll
    for (int nt = 0; nt < 4; ++nt) { acc[nt][0]=0.f; acc[nt][1]=0.f; acc[nt][2]=0.f; acc[nt][3]=0.f; }

    const int token0 = mtile * 64;
    for (int chunk = 0; chunk < 4; ++chunk) {
        const int cell = ksplit * 4 + chunk;
        const int py = cell >> 3, px = cell & 7;
        __syncthreads();
#pragma unroll
        for (int p = 0; p < 4; ++p) {
            int idx = p * 256 + tid;
            int r = idx >> 4, c4 = (idx & 15) * 4;
            int token = token0 + r;
            int b = token >> 8, rm = token & 255;
            int oy = rm >> 4, ox = rm & 15;
            int y = oy * 8 + py, xc = ox * 8 + px;
            f4 xv = *(const f4*)(x + ((size_t)(b * 16384 + y * 128 + xc)) * 64 + c4);
            short4v s;
#pragma unroll
            for (int j = 0; j < 4; ++j) s[j] = (short)f2bf(xv[j]);
            *(short4v*)&sA[r * 72 + c4] = s;
        }
#pragma unroll
        for (int p = 0; p < 2; ++p) {
            int idx = p * 256 + tid;
            int co = idx >> 3, g = (idx & 7) * 8;
            *(short8*)&sB[co * 72 + g] =
                *(const short8*)(WsrT + (size_t)cell * 4096 + co * 64 + g);
        }
        __syncthreads();
#pragma unroll
        for (int ks = 0; ks < 2; ++ks) {
            short8 af = *(const short8*)&sA[(wave * 16 + l15) * 72 + ks * 32 + quad * 8];
#pragma unroll
            for (int nt = 0; nt < 4; ++nt) {
                short8 bf = *(const short8*)&sB[(nt * 16 + l15) * 72 + ks * 32 + quad * 8];
                acc[nt] = MFMA16(af, bf, acc[nt]);
            }
        }
    }
    float* outp = partials + (size_t)ksplit * 131072;
#pragma unroll
    for (int nt = 0; nt < 4; ++nt)
#pragma unroll
        for (int i = 0; i < 4; ++i) {
            int row = token0 + wave * 16 + quad * 4 + i;
            outp[(size_t)row * 64 + nt * 16 + l15] = acc[nt][i];
        }
}

// ---------------------------------------------------------------------------
// Kernel 2: reduce 16 partials + bias + LayerNorm + K/V proj (vector ALU).
// Grid 512 x 256 thr; one wave per kv token. No barriers.
// (Round-0 proven version.)
// ---------------------------------------------------------------------------
__global__ __launch_bounds__(256) void lnkv_kernel(
    const float* __restrict__ partials, const float* __restrict__ bsr,
    const float* __restrict__ gamma, const float* __restrict__ beta,
    const float* __restrict__ Wk, const float* __restrict__ bk,
    const float* __restrict__ Wv, const float* __restrict__ bv,
    u16* __restrict__ kbuf, u16* __restrict__ vTbuf)
{
    const int wave = threadIdx.x >> 6;
    const int c    = threadIdx.x & 63;
    const int token = blockIdx.x * 4 + wave;

    float acc = 0.f;
#pragma unroll
    for (int s = 0; s < 16; ++s)
        acc += partials[(size_t)s * 131072 + (size_t)token * 64 + c];
    acc += bsr[c];

    float sum = acc, sumsq = acc * acc;
#pragma unroll
    for (int m = 1; m < 64; m <<= 1) {
        sum   += __shfl_xor(sum, m, 64);
        sumsq += __shfl_xor(sumsq, m, 64);
    }
    float mean = sum * (1.f / 64.f);
    float var  = sumsq * (1.f / 64.f) - mean * mean;
    float inv  = rsqrtf(var + 1e-5f);
    float xn   = (acc - mean) * inv * gamma[c] + beta[c];

    __shared__ float sxn[4][64];
    sxn[wave][c] = xn;

    float ka = bk[c], va = bv[c];
#pragma unroll 8
    for (int ci = 0; ci < 64; ++ci) {
        float xv = sxn[wave][ci];
        ka += xv * Wk[ci * 64 + c];
        va += xv * Wv[ci * 64 + c];
    }
    kbuf[(size_t)token * 64 + c] = f2bf(ka);
    int b = token >> 8, t = token & 255;
    vTbuf[(size_t)b * 16384 + c * 256 + t] = f2bf(va);
}

// ---------------------------------------------------------------------------
// Kernel 3 (RESTRUCTURED): fused q-proj + attention + out-proj.
// Grid 512 (8 batches x 64 tiles of 256 q-rows), 512 thr = 8 waves.
// Changes vs round-0:
//  (a) loop-fission over the two q-quads (qt): full chain per qt. Peak live
//      set halves (st[16]=64 + pf=32 + misc ~ 110 VGPR) -> fits the 128-VGPR
//      allocation with NO SPILLS (round-2 evidence: 2-qt version spilled
//      ~250 f32/thread at the 128 cap).
//  (b) sWq/sWp dropped from LDS; Wq/Wp fragments read directly from the
//      8 KB L2/L1-resident WqT/WpT. LDS 89 -> 69 KB.
//  (c) __launch_bounds__(512, 4): 4 waves/SIMD = 16 waves/CU = 2 blocks/CU.
//      Block A's MFMA phase now overlaps block B's staging drain.
// Cost: sK/sV fragments read twice from LDS (LDS BW is not a bottleneck).
// ---------------------------------------------------------------------------
__global__ __launch_bounds__(512, 4) void attn_kernel(
    const float* __restrict__ x, const u16* __restrict__ WqT,
    const float* __restrict__ bq, const u16* __restrict__ WpT,
    const float* __restrict__ bp, const u16* __restrict__ kbuf,
    const u16* __restrict__ vTbuf, float* __restrict__ out)
{
    const int batch = blockIdx.x >> 6;
    const int row0  = (blockIdx.x & 63) * 256;
    const int tid  = threadIdx.x;
    const int wave = tid >> 6;
    const int lane = tid & 63;
    const int l15  = lane & 15;
    const int quad = lane >> 4;

    __shared__ u16 sK[256 * 72];      // k[token][d]      36.0 KB
    __shared__ u16 sV[64 * 264];      // vT[d][token]     33.8 KB
                                      // total 69.0 KB -> 2 blocks/CU

    const int qbase = row0 + wave * 32;   // this wave's 32 q-rows (16 per qt)

    // ---- hoisted pass-0 x loads: issue BEFORE staging, consume after barrier
    f4 xq0[4];
#pragma unroll
    for (int kt = 0; kt < 4; ++kt)
        xq0[kt] = *(const f4*)(x + ((size_t)(batch * 16384 + qbase + l15)) * 64 + kt * 16 + quad * 4);

    // ---- staging (only barrier in the kernel) ----
#pragma unroll
    for (int p = 0; p < 4; ++p) {
        int idx = p * 512 + tid; int tt = idx >> 3, seg = idx & 7;
        *(short8*)&sK[tt * 72 + seg * 8] =
            *(const short8*)(kbuf + ((size_t)(batch * 256 + tt)) * 64 + seg * 8);
    }
#pragma unroll
    for (int p = 0; p < 4; ++p) {
        int idx = p * 512 + tid; int d = idx >> 5, seg = idx & 31;
        *(short8*)&sV[d * 264 + seg * 8] =
            *(const short8*)(vTbuf + ((size_t)(batch * 64 + d)) * 256 + seg * 8);
    }
    __syncthreads();

    for (int qt = 0; qt < 2; ++qt) {
        const int qrow = qbase + qt * 16 + l15;   // this lane's q-row this pass

        // ---- x fragments for this pass ----
        f4 xq[4];
        if (qt == 0) {
#pragma unroll
            for (int kt = 0; kt < 4; ++kt) xq[kt] = xq0[kt];
        } else {
#pragma unroll
            for (int kt = 0; kt < 4; ++kt)
                xq[kt] = *(const f4*)(x + ((size_t)(batch * 16384 + qrow)) * 64 + kt * 16 + quad * 4);
        }

        // ---- q^T = Wq^T @ x^T  (A straight from global WqT; B = x regs) ----
        f32x4 qT[4];
#pragma unroll
        for (int ct = 0; ct < 4; ++ct) { qT[ct][0]=0.f; qT[ct][1]=0.f; qT[ct][2]=0.f; qT[ct][3]=0.f; }
#pragma unroll
        for (int kt = 0; kt < 4; ++kt) {
            short4v bfr = pack4(xq[kt]);
#pragma unroll
            for (int ct = 0; ct < 4; ++ct) {
                short4v a = *(const short4v*)(WqT + (size_t)(ct * 16 + l15) * 64 + kt * 16 + quad * 4);
                qT[ct] = MFMA1K(a, bfr, qT[ct]);
            }
        }
        // bias + 1/sqrt(64), convert to B-frags for S^T
        short4v qf[4];
#pragma unroll
        for (int ct = 0; ct < 4; ++ct) {
            f4 bqv = *(const f4*)(bq + ct * 16 + quad * 4);
            f4 t;
#pragma unroll
            for (int i = 0; i < 4; ++i) t[i] = (qT[ct][i] + bqv[i]) * 0.125f;
            qf[ct] = pack4(t);
        }

        // ---- S^T = K @ q^T  (A from sK; B = qf in registers) ----
        f32x4 st[16];
#pragma unroll
        for (int mt = 0; mt < 16; ++mt) { st[mt][0]=0.f; st[mt][1]=0.f; st[mt][2]=0.f; st[mt][3]=0.f; }
#pragma unroll
        for (int mt = 0; mt < 16; ++mt)
#pragma unroll
            for (int kt = 0; kt < 4; ++kt) {
                short4v a = *(const short4v*)&sK[(mt * 16 + l15) * 72 + kt * 16 + quad * 4];
                st[mt] = MFMA1K(a, qf[kt], st[mt]);
            }

        // ---- softmax over k: in-lane 64 + 2 cross-quad shuffles ----
        short4v pf[16];
        float mx = -1e30f;
#pragma unroll
        for (int mt = 0; mt < 16; ++mt)
#pragma unroll
            for (int i = 0; i < 4; ++i) mx = fmaxf(mx, st[mt][i]);
        mx = fmaxf(mx, __shfl_xor(mx, 16, 64));
        mx = fmaxf(mx, __shfl_xor(mx, 32, 64));
        float l = 0.f;
#pragma unroll
        for (int mt = 0; mt < 16; ++mt) {
            f4 e;
#pragma unroll
            for (int i = 0; i < 4; ++i) { e[i] = __expf(st[mt][i] - mx); l += e[i]; }
            pf[mt] = pack4(e);
        }
        l += __shfl_xor(l, 16, 64);
        l += __shfl_xor(l, 32, 64);
        const float linv = 1.0f / l;

        // ---- O^T = V^T @ P^T  (A from sV; B = pf in registers) ----
        f32x4 ot[4];
#pragma unroll
        for (int dt = 0; dt < 4; ++dt) { ot[dt][0]=0.f; ot[dt][1]=0.f; ot[dt][2]=0.f; ot[dt][3]=0.f; }
#pragma unroll
        for (int mt = 0; mt < 16; ++mt)
#pragma unroll
            for (int dt = 0; dt < 4; ++dt) {
                short4v a = *(const short4v*)&sV[(dt * 16 + l15) * 264 + mt * 16 + quad * 4];
                ot[dt] = MFMA1K(a, pf[mt], ot[dt]);
            }

        // ---- final^T = Wp^T @ (O^T / l)  (A from global WpT; B regs) ----
        short4v of[4];
#pragma unroll
        for (int dt = 0; dt < 4; ++dt) {
            f4 t;
#pragma unroll
            for (int i = 0; i < 4; ++i) t[i] = ot[dt][i] * linv;
            of[dt] = pack4(t);
        }
        f32x4 ft[4];
#pragma unroll
        for (int ct = 0; ct < 4; ++ct) { ft[ct][0]=0.f; ft[ct][1]=0.f; ft[ct][2]=0.f; ft[ct][3]=0.f; }
#pragma unroll
        for (int kt = 0; kt < 4; ++kt)
#pragma unroll
            for (int ct = 0; ct < 4; ++ct) {
                short4v a = *(const short4v*)(WpT + (size_t)(ct * 16 + l15) * 64 + kt * 16 + quad * 4);
                ft[ct] = MFMA1K(a, of[kt], ft[ct]);
            }

        // ---- store: lane holds 4 consecutive channels of one row -> dwordx4 ----
#pragma unroll
        for (int ct = 0; ct < 4; ++ct) {
            f4 bpv = *(const f4*)(bp + ct * 16 + quad * 4);
            f4 r;
#pragma unroll
            for (int i = 0; i < 4; ++i) r[i] = ft[ct][i] + bpv[i];
            *(f4*)(out + ((size_t)(batch * 16384 + qrow)) * 64 + ct * 16 + quad * 4) = r;
        }
    }
}

// ---------------------------------------------------------------------------
extern "C" void kernel_launch(void* const* d_in, const int* in_sizes, int n_in,
                              void* d_out, int out_size, void* d_ws, size_t ws_size,
                              hipStream_t stream) {
    const float* x     = (const float*)d_in[0];
    const float* Wq    = (const float*)d_in[1];
    const float* bq    = (const float*)d_in[2];
    const float* Wk    = (const float*)d_in[3];
    const float* bk    = (const float*)d_in[4];
    const float* Wv    = (const float*)d_in[5];
    const float* bv    = (const float*)d_in[6];
    const float* Wsr   = (const float*)d_in[7];
    const float* bsr   = (const float*)d_in[8];
    const float* gamma = (const float*)d_in[9];
    const float* beta  = (const float*)d_in[10];
    const float* Wp    = (const float*)d_in[11];
    const float* bp    = (const float*)d_in[12];

    char* w = (char*)d_ws;
    float* partials = (float*)w;                         // 16*2048*64 f32 = 8.4 MB
    u16* kbuf  = (u16*)(w + 8388608);                    // 256 KB
    u16* vTbuf = (u16*)(w + 8388608 + 262144);           // 256 KB
    u16* WsrT  = (u16*)(w + 8388608 + 524288);           // 512 KB
    u16* WqT   = (u16*)(w + 8388608 + 524288 + 524288);  // 8 KB
    u16* WpT   = (u16*)(w + 8388608 + 524288 + 524288 + 8192);
    float* out = (float*)d_out;

    prep_kernel<<<66, 256, 0, stream>>>(Wsr, Wq, Wp, WsrT, WqT, WpT);
    conv_partial_kernel<<<512, 256, 0, stream>>>(x, WsrT, partials);
    lnkv_kernel<<<512, 256, 0, stream>>>(partials, bsr, gamma, beta, Wk, bk, Wv, bv, kbuf, vTbuf);
    attn_kernel<<<512, 512, 0, stream>>>(x, WqT, bq, WpT, bp, kbuf, vTbuf, out);
}

// Round 5
// 246.023 us; speedup vs baseline: 1.5171x; 1.5171x over previous
//
#include <hip/hip_runtime.h>

typedef unsigned short u16;
typedef short short8 __attribute__((ext_vector_type(8)));
typedef short short4v __attribute__((ext_vector_type(4)));
typedef float f32x4 __attribute__((ext_vector_type(4)));
typedef float f4 __attribute__((ext_vector_type(4)));

#define MFMA16(a, b, c) __builtin_amdgcn_mfma_f32_16x16x32_bf16(a, b, c, 0, 0, 0)
// K=16 variant: B-fragment layout == C/D layout -> chain MFMAs in registers
#define MFMA1K(a, b, c) __builtin_amdgcn_mfma_f32_16x16x16bf16_1k(a, b, c, 0, 0, 0)

__device__ inline u16 f2bf(float f) {
    unsigned int v = __builtin_bit_cast(unsigned int, f);
    unsigned int r = (v + 0x7FFFu + ((v >> 16) & 1u)) >> 16;
    return (u16)r;
}
__device__ inline short4v pack4(f4 v) {
    short4v r;
#pragma unroll
    for (int j = 0; j < 4; ++j) r[j] = (short)f2bf(v[j]);
    return r;
}

// ---------------------------------------------------------------------------
// Kernel 0: one-time weight prep. Transpose Wsr (per tap), Wq, Wp to bf16
// [co][ci] row-major in ws. Grid 66: bid<64 = tap, 64 = Wq, 65 = Wp.
// ---------------------------------------------------------------------------
__global__ __launch_bounds__(256) void prep_kernel(
    const float* __restrict__ Wsr, const float* __restrict__ Wq,
    const float* __restrict__ Wp,
    u16* __restrict__ WsrT, u16* __restrict__ WqT, u16* __restrict__ WpT)
{
    const int bid = blockIdx.x;
    const int tid = threadIdx.x;
    __shared__ float sT[64 * 65];
    const float* src;
    u16* dst;
    if (bid < 64)      { src = Wsr + (size_t)bid * 4096; dst = WsrT + (size_t)bid * 4096; }
    else if (bid == 64){ src = Wq;  dst = WqT; }
    else               { src = Wp;  dst = WpT; }
#pragma unroll
    for (int p = 0; p < 4; ++p) {
        int idx = p * 256 + tid;
        int r = idx >> 4, c4 = (idx & 15) * 4;
        f4 v = *(const f4*)(src + r * 64 + c4);
#pragma unroll
        for (int j = 0; j < 4; ++j) sT[r * 65 + c4 + j] = v[j];
    }
    __syncthreads();
#pragma unroll
    for (int p = 0; p < 2; ++p) {
        int idx = p * 256 + tid;
        int co = idx >> 3, g = (idx & 7) * 8;
        short8 o;
#pragma unroll
        for (int j = 0; j < 8; ++j) o[j] = (short)f2bf(sT[(g + j) * 65 + co]);
        *(short8*)(dst + (size_t)co * 64 + g) = o;
    }
}

// ---------------------------------------------------------------------------
// Kernel 1: split-K conv partials. Grid 512 = 16 ksplits x 32 mtiles
// (2 blocks/CU for latency hiding, 4 serial taps each).
// fp32 partials [16][2048][64].  (Round-0 proven LDS-staged version.)
// ---------------------------------------------------------------------------
__global__ __launch_bounds__(256) void conv_partial_kernel(
    const float* __restrict__ x, const u16* __restrict__ WsrT,
    float* __restrict__ partials)
{
    const int mtile  = blockIdx.x & 31;
    const int ksplit = blockIdx.x >> 5;
    const int tid  = threadIdx.x;
    const int wave = tid >> 6;
    const int lane = tid & 63;
    const int l15  = lane & 15;
    const int quad = lane >> 4;

    __shared__ u16 sA[64 * 72];
    __shared__ u16 sB[64 * 72];

    f32x4 acc[4];
#pragma unroll
    for (int nt = 0; nt < 4; ++nt) { acc[nt][0]=0.f; acc[nt][1]=0.f; acc[nt][2]=0.f; acc[nt][3]=0.f; }

    const int token0 = mtile * 64;
    for (int chunk = 0; chunk < 4; ++chunk) {
        const int cell = ksplit * 4 + chunk;
        const int py = cell >> 3, px = cell & 7;
        __syncthreads();
#pragma unroll
        for (int p = 0; p < 4; ++p) {
            int idx = p * 256 + tid;
            int r = idx >> 4, c4 = (idx & 15) * 4;
            int token = token0 + r;
            int b = token >> 8, rm = token & 255;
            int oy = rm >> 4, ox = rm & 15;
            int y = oy * 8 + py, xc = ox * 8 + px;
            f4 xv = *(const f4*)(x + ((size_t)(b * 16384 + y * 128 + xc)) * 64 + c4);
            short4v s;
#pragma unroll
            for (int j = 0; j < 4; ++j) s[j] = (short)f2bf(xv[j]);
            *(short4v*)&sA[r * 72 + c4] = s;
        }
#pragma unroll
        for (int p = 0; p < 2; ++p) {
            int idx = p * 256 + tid;
            int co = idx >> 3, g = (idx & 7) * 8;
            *(short8*)&sB[co * 72 + g] =
                *(const short8*)(WsrT + (size_t)cell * 4096 + co * 64 + g);
        }
        __syncthreads();
#pragma unroll
        for (int ks = 0; ks < 2; ++ks) {
            short8 af = *(const short8*)&sA[(wave * 16 + l15) * 72 + ks * 32 + quad * 8];
#pragma unroll
            for (int nt = 0; nt < 4; ++nt) {
                short8 bf = *(const short8*)&sB[(nt * 16 + l15) * 72 + ks * 32 + quad * 8];
                acc[nt] = MFMA16(af, bf, acc[nt]);
            }
        }
    }
    float* outp = partials + (size_t)ksplit * 131072;
#pragma unroll
    for (int nt = 0; nt < 4; ++nt)
#pragma unroll
        for (int i = 0; i < 4; ++i) {
            int row = token0 + wave * 16 + quad * 4 + i;
            outp[(size_t)row * 64 + nt * 16 + l15] = acc[nt][i];
        }
}

// ---------------------------------------------------------------------------
// Kernel 2: reduce 16 partials + bias + LayerNorm + K/V proj (vector ALU).
// Grid 512 x 256 thr; one wave per kv token. No barriers.
// (Round-0 proven version.)
// ---------------------------------------------------------------------------
__global__ __launch_bounds__(256) void lnkv_kernel(
    const float* __restrict__ partials, const float* __restrict__ bsr,
    const float* __restrict__ gamma, const float* __restrict__ beta,
    const float* __restrict__ Wk, const float* __restrict__ bk,
    const float* __restrict__ Wv, const float* __restrict__ bv,
    u16* __restrict__ kbuf, u16* __restrict__ vTbuf)
{
    const int wave = threadIdx.x >> 6;
    const int c    = threadIdx.x & 63;
    const int token = blockIdx.x * 4 + wave;

    float acc = 0.f;
#pragma unroll
    for (int s = 0; s < 16; ++s)
        acc += partials[(size_t)s * 131072 + (size_t)token * 64 + c];
    acc += bsr[c];

    float sum = acc, sumsq = acc * acc;
#pragma unroll
    for (int m = 1; m < 64; m <<= 1) {
        sum   += __shfl_xor(sum, m, 64);
        sumsq += __shfl_xor(sumsq, m, 64);
    }
    float mean = sum * (1.f / 64.f);
    float var  = sumsq * (1.f / 64.f) - mean * mean;
    float inv  = rsqrtf(var + 1e-5f);
    float xn   = (acc - mean) * inv * gamma[c] + beta[c];

    __shared__ float sxn[4][64];
    sxn[wave][c] = xn;

    float ka = bk[c], va = bv[c];
#pragma unroll 8
    for (int ci = 0; ci < 64; ++ci) {
        float xv = sxn[wave][ci];
        ka += xv * Wk[ci * 64 + c];
        va += xv * Wv[ci * 64 + c];
    }
    kbuf[(size_t)token * 64 + c] = f2bf(ka);
    int b = token >> 8, t = token & 255;
    vTbuf[(size_t)b * 16384 + c * 256 + t] = f2bf(va);
}

// ---------------------------------------------------------------------------
// Kernel 3: fused q-proj + attention + out-proj, fissioned over q-quads.
// Grid 512 (8 batches x 64 tiles of 256 q-rows), 512 thr = 8 waves.
//  (a) loop-fission over qt: full chain per 16 q-rows. Peak live set ~115
//      VGPR (st[16]=64 + pf[16]=32 + misc) -> fits without spilling.
//  (b) sWq/sWp not staged; Wq/Wp fragments read from 8 KB L1/L2-resident
//      WqT/WpT. LDS 69 KB.
//  (c) __launch_bounds__(512) ONLY — round-4's (512,4) made the allocator
//      pick 64 VGPRs and spill ~750 MB of scratch (270 µs). Let the
//      allocator size to the live set; no-spill >> occupancy here.
// ---------------------------------------------------------------------------
__global__ __launch_bounds__(512) void attn_kernel(
    const float* __restrict__ x, const u16* __restrict__ WqT,
    const float* __restrict__ bq, const u16* __restrict__ WpT,
    const float* __restrict__ bp, const u16* __restrict__ kbuf,
    const u16* __restrict__ vTbuf, float* __restrict__ out)
{
    const int batch = blockIdx.x >> 6;
    const int row0  = (blockIdx.x & 63) * 256;
    const int tid  = threadIdx.x;
    const int wave = tid >> 6;
    const int lane = tid & 63;
    const int l15  = lane & 15;
    const int quad = lane >> 4;

    __shared__ u16 sK[256 * 72];      // k[token][d]      36.0 KB
    __shared__ u16 sV[64 * 264];      // vT[d][token]     33.8 KB
                                      // total 69.0 KB

    const int qbase = row0 + wave * 32;   // this wave's 32 q-rows (16 per qt)

    // ---- hoisted pass-0 x loads: issue BEFORE staging, consume after barrier
    f4 xq0[4];
#pragma unroll
    for (int kt = 0; kt < 4; ++kt)
        xq0[kt] = *(const f4*)(x + ((size_t)(batch * 16384 + qbase + l15)) * 64 + kt * 16 + quad * 4);

    // ---- staging (only barrier in the kernel) ----
#pragma unroll
    for (int p = 0; p < 4; ++p) {
        int idx = p * 512 + tid; int tt = idx >> 3, seg = idx & 7;
        *(short8*)&sK[tt * 72 + seg * 8] =
            *(const short8*)(kbuf + ((size_t)(batch * 256 + tt)) * 64 + seg * 8);
    }
#pragma unroll
    for (int p = 0; p < 4; ++p) {
        int idx = p * 512 + tid; int d = idx >> 5, seg = idx & 31;
        *(short8*)&sV[d * 264 + seg * 8] =
            *(const short8*)(vTbuf + ((size_t)(batch * 64 + d)) * 256 + seg * 8);
    }
    __syncthreads();

    for (int qt = 0; qt < 2; ++qt) {
        const int qrow = qbase + qt * 16 + l15;   // this lane's q-row this pass

        // ---- x fragments for this pass ----
        f4 xq[4];
        if (qt == 0) {
#pragma unroll
            for (int kt = 0; kt < 4; ++kt) xq[kt] = xq0[kt];
        } else {
#pragma unroll
            for (int kt = 0; kt < 4; ++kt)
                xq[kt] = *(const f4*)(x + ((size_t)(batch * 16384 + qrow)) * 64 + kt * 16 + quad * 4);
        }

        // ---- q^T = Wq^T @ x^T  (A straight from global WqT; B = x regs) ----
        f32x4 qT[4];
#pragma unroll
        for (int ct = 0; ct < 4; ++ct) { qT[ct][0]=0.f; qT[ct][1]=0.f; qT[ct][2]=0.f; qT[ct][3]=0.f; }
#pragma unroll
        for (int kt = 0; kt < 4; ++kt) {
            short4v bfr = pack4(xq[kt]);
#pragma unroll
            for (int ct = 0; ct < 4; ++ct) {
                short4v a = *(const short4v*)(WqT + (size_t)(ct * 16 + l15) * 64 + kt * 16 + quad * 4);
                qT[ct] = MFMA1K(a, bfr, qT[ct]);
            }
        }
        // bias + 1/sqrt(64), convert to B-frags for S^T
        short4v qf[4];
#pragma unroll
        for (int ct = 0; ct < 4; ++ct) {
            f4 bqv = *(const f4*)(bq + ct * 16 + quad * 4);
            f4 t;
#pragma unroll
            for (int i = 0; i < 4; ++i) t[i] = (qT[ct][i] + bqv[i]) * 0.125f;
            qf[ct] = pack4(t);
        }

        // ---- S^T = K @ q^T  (A from sK; B = qf in registers) ----
        f32x4 st[16];
#pragma unroll
        for (int mt = 0; mt < 16; ++mt) { st[mt][0]=0.f; st[mt][1]=0.f; st[mt][2]=0.f; st[mt][3]=0.f; }
#pragma unroll
        for (int mt = 0; mt < 16; ++mt)
#pragma unroll
            for (int kt = 0; kt < 4; ++kt) {
                short4v a = *(const short4v*)&sK[(mt * 16 + l15) * 72 + kt * 16 + quad * 4];
                st[mt] = MFMA1K(a, qf[kt], st[mt]);
            }

        // ---- softmax over k: in-lane 64 + 2 cross-quad shuffles ----
        short4v pf[16];
        float mx = -1e30f;
#pragma unroll
        for (int mt = 0; mt < 16; ++mt)
#pragma unroll
            for (int i = 0; i < 4; ++i) mx = fmaxf(mx, st[mt][i]);
        mx = fmaxf(mx, __shfl_xor(mx, 16, 64));
        mx = fmaxf(mx, __shfl_xor(mx, 32, 64));
        float l = 0.f;
#pragma unroll
        for (int mt = 0; mt < 16; ++mt) {
            f4 e;
#pragma unroll
            for (int i = 0; i < 4; ++i) { e[i] = __expf(st[mt][i] - mx); l += e[i]; }
            pf[mt] = pack4(e);
        }
        l += __shfl_xor(l, 16, 64);
        l += __shfl_xor(l, 32, 64);
        const float linv = 1.0f / l;

        // ---- O^T = V^T @ P^T  (A from sV; B = pf in registers) ----
        f32x4 ot[4];
#pragma unroll
        for (int dt = 0; dt < 4; ++dt) { ot[dt][0]=0.f; ot[dt][1]=0.f; ot[dt][2]=0.f; ot[dt][3]=0.f; }
#pragma unroll
        for (int mt = 0; mt < 16; ++mt)
#pragma unroll
            for (int dt = 0; dt < 4; ++dt) {
                short4v a = *(const short4v*)&sV[(dt * 16 + l15) * 264 + mt * 16 + quad * 4];
                ot[dt] = MFMA1K(a, pf[mt], ot[dt]);
            }

        // ---- final^T = Wp^T @ (O^T / l)  (A from global WpT; B regs) ----
        short4v of[4];
#pragma unroll
        for (int dt = 0; dt < 4; ++dt) {
            f4 t;
#pragma unroll
            for (int i = 0; i < 4; ++i) t[i] = ot[dt][i] * linv;
            of[dt] = pack4(t);
        }
        f32x4 ft[4];
#pragma unroll
        for (int ct = 0; ct < 4; ++ct) { ft[ct][0]=0.f; ft[ct][1]=0.f; ft[ct][2]=0.f; ft[ct][3]=0.f; }
#pragma unroll
        for (int kt = 0; kt < 4; ++kt)
#pragma unroll
            for (int ct = 0; ct < 4; ++ct) {
                short4v a = *(const short4v*)(WpT + (size_t)(ct * 16 + l15) * 64 + kt * 16 + quad * 4);
                ft[ct] = MFMA1K(a, of[kt], ft[ct]);
            }

        // ---- store: lane holds 4 consecutive channels of one row -> dwordx4 ----
#pragma unroll
        for (int ct = 0; ct < 4; ++ct) {
            f4 bpv = *(const f4*)(bp + ct * 16 + quad * 4);
            f4 r;
#pragma unroll
            for (int i = 0; i < 4; ++i) r[i] = ft[ct][i] + bpv[i];
            *(f4*)(out + ((size_t)(batch * 16384 + qrow)) * 64 + ct * 16 + quad * 4) = r;
        }
    }
}

// ---------------------------------------------------------------------------
extern "C" void kernel_launch(void* const* d_in, const int* in_sizes, int n_in,
                              void* d_out, int out_size, void* d_ws, size_t ws_size,
                              hipStream_t stream) {
    const float* x     = (const float*)d_in[0];
    const float* Wq    = (const float*)d_in[1];
    const float* bq    = (const float*)d_in[2];
    const float* Wk    = (const float*)d_in[3];
    const float* bk    = (const float*)d_in[4];
    const float* Wv    = (const float*)d_in[5];
    const float* bv    = (const float*)d_in[6];
    const float* Wsr   = (const float*)d_in[7];
    const float* bsr   = (const float*)d_in[8];
    const float* gamma = (const float*)d_in[9];
    const float* beta  = (const float*)d_in[10];
    const float* Wp    = (const float*)d_in[11];
    const float* bp    = (const float*)d_in[12];

    char* w = (char*)d_ws;
    float* partials = (float*)w;                         // 16*2048*64 f32 = 8.4 MB
    u16* kbuf  = (u16*)(w + 8388608);                    // 256 KB
    u16* vTbuf = (u16*)(w + 8388608 + 262144);           // 256 KB
    u16* WsrT  = (u16*)(w + 8388608 + 524288);           // 512 KB
    u16* WqT   = (u16*)(w + 8388608 + 524288 + 524288);  // 8 KB
    u16* WpT   = (u16*)(w + 8388608 + 524288 + 524288 + 8192);
    float* out = (float*)d_out;

    prep_kernel<<<66, 256, 0, stream>>>(Wsr, Wq, Wp, WsrT, WqT, WpT);
    conv_partial_kernel<<<512, 256, 0, stream>>>(x, WsrT, partials);
    lnkv_kernel<<<512, 256, 0, stream>>>(partials, bsr, gamma, beta, Wk, bk, Wv, bv, kbuf, vTbuf);
    attn_kernel<<<512, 512, 0, stream>>>(x, WqT, bq, WpT, bp, kbuf, vTbuf, out);
}

// Round 6
// 144.872 us; speedup vs baseline: 2.5763x; 1.6982x over previous
//
#include <hip/hip_runtime.h>

typedef unsigned short u16;
typedef short short8 __attribute__((ext_vector_type(8)));
typedef short short4v __attribute__((ext_vector_type(4)));
typedef float f32x4 __attribute__((ext_vector_type(4)));
typedef float f4 __attribute__((ext_vector_type(4)));

#define MFMA16(a, b, c) __builtin_amdgcn_mfma_f32_16x16x32_bf16(a, b, c, 0, 0, 0)
// K=16 variant: B-fragment layout == C/D layout -> chain MFMAs in registers
#define MFMA1K(a, b, c) __builtin_amdgcn_mfma_f32_16x16x16bf16_1k(a, b, c, 0, 0, 0)

__device__ inline u16 f2bf(float f) {
    unsigned int v = __builtin_bit_cast(unsigned int, f);
    unsigned int r = (v + 0x7FFFu + ((v >> 16) & 1u)) >> 16;
    return (u16)r;
}
__device__ inline short4v pack4(f4 v) {
    short4v r;
#pragma unroll
    for (int j = 0; j < 4; ++j) r[j] = (short)f2bf(v[j]);
    return r;
}

// ---------------------------------------------------------------------------
// Kernel 0: one-time weight prep. Transpose Wsr (per tap), Wq, Wp to bf16
// [co][ci] row-major in ws. Grid 66: bid<64 = tap, 64 = Wq, 65 = Wp.
// ---------------------------------------------------------------------------
__global__ __launch_bounds__(256) void prep_kernel(
    const float* __restrict__ Wsr, const float* __restrict__ Wq,
    const float* __restrict__ Wp,
    u16* __restrict__ WsrT, u16* __restrict__ WqT, u16* __restrict__ WpT)
{
    const int bid = blockIdx.x;
    const int tid = threadIdx.x;
    __shared__ float sT[64 * 65];
    const float* src;
    u16* dst;
    if (bid < 64)      { src = Wsr + (size_t)bid * 4096; dst = WsrT + (size_t)bid * 4096; }
    else if (bid == 64){ src = Wq;  dst = WqT; }
    else               { src = Wp;  dst = WpT; }
#pragma unroll
    for (int p = 0; p < 4; ++p) {
        int idx = p * 256 + tid;
        int r = idx >> 4, c4 = (idx & 15) * 4;
        f4 v = *(const f4*)(src + r * 64 + c4);
#pragma unroll
        for (int j = 0; j < 4; ++j) sT[r * 65 + c4 + j] = v[j];
    }
    __syncthreads();
#pragma unroll
    for (int p = 0; p < 2; ++p) {
        int idx = p * 256 + tid;
        int co = idx >> 3, g = (idx & 7) * 8;
        short8 o;
#pragma unroll
        for (int j = 0; j < 8; ++j) o[j] = (short)f2bf(sT[(g + j) * 65 + co]);
        *(short8*)(dst + (size_t)co * 64 + g) = o;
    }
}

// ---------------------------------------------------------------------------
// Kernel 1 (RESTRUCTURED): split-K conv partials, single-barrier staging.
// Grid 512 = 16 ksplits x 32 mtiles (2 blocks/CU), 4 taps each.
// Round-0 version paid 4x {barrier; ~900-cy stage drain; barrier; 8 MFMA}.
// Now: stage ALL 4 chunks into sA[4]/sB[4] (72 KB LDS, still 2 blocks/CU),
// 24 independent global loads issued back-to-back -> ONE latency drain,
// ONE barrier, then all 32 MFMAs. Fragment values identical to round-0.
// fp32 partials [16][2048][64].
// ---------------------------------------------------------------------------
__global__ __launch_bounds__(256) void conv_partial_kernel(
    const float* __restrict__ x, const u16* __restrict__ WsrT,
    float* __restrict__ partials)
{
    const int mtile  = blockIdx.x & 31;
    const int ksplit = blockIdx.x >> 5;
    const int tid  = threadIdx.x;
    const int wave = tid >> 6;
    const int lane = tid & 63;
    const int l15  = lane & 15;
    const int quad = lane >> 4;

    __shared__ u16 sA[4][64 * 72];   // 36 KB
    __shared__ u16 sB[4][64 * 72];   // 36 KB

    const int token0 = mtile * 64;

    // ---- stage all 4 chunks, no intervening barriers ----
#pragma unroll
    for (int chunk = 0; chunk < 4; ++chunk) {
        const int cell = ksplit * 4 + chunk;
        const int py = cell >> 3, px = cell & 7;
#pragma unroll
        for (int p = 0; p < 4; ++p) {
            int idx = p * 256 + tid;
            int r = idx >> 4, c4 = (idx & 15) * 4;
            int token = token0 + r;
            int b = token >> 8, rm = token & 255;
            int oy = rm >> 4, ox = rm & 15;
            int y = oy * 8 + py, xc = ox * 8 + px;
            f4 xv = *(const f4*)(x + ((size_t)(b * 16384 + y * 128 + xc)) * 64 + c4);
            short4v s;
#pragma unroll
            for (int j = 0; j < 4; ++j) s[j] = (short)f2bf(xv[j]);
            *(short4v*)&sA[chunk][r * 72 + c4] = s;
        }
#pragma unroll
        for (int p = 0; p < 2; ++p) {
            int idx = p * 256 + tid;
            int co = idx >> 3, g = (idx & 7) * 8;
            *(short8*)&sB[chunk][co * 72 + g] =
                *(const short8*)(WsrT + (size_t)cell * 4096 + co * 64 + g);
        }
    }
    __syncthreads();   // the only barrier

    f32x4 acc[4];
#pragma unroll
    for (int nt = 0; nt < 4; ++nt) { acc[nt][0]=0.f; acc[nt][1]=0.f; acc[nt][2]=0.f; acc[nt][3]=0.f; }

#pragma unroll
    for (int chunk = 0; chunk < 4; ++chunk) {
#pragma unroll
        for (int ks = 0; ks < 2; ++ks) {
            short8 af = *(const short8*)&sA[chunk][(wave * 16 + l15) * 72 + ks * 32 + quad * 8];
#pragma unroll
            for (int nt = 0; nt < 4; ++nt) {
                short8 bf = *(const short8*)&sB[chunk][(nt * 16 + l15) * 72 + ks * 32 + quad * 8];
                acc[nt] = MFMA16(af, bf, acc[nt]);
            }
        }
    }
    float* outp = partials + (size_t)ksplit * 131072;
#pragma unroll
    for (int nt = 0; nt < 4; ++nt)
#pragma unroll
        for (int i = 0; i < 4; ++i) {
            int row = token0 + wave * 16 + quad * 4 + i;
            outp[(size_t)row * 64 + nt * 16 + l15] = acc[nt][i];
        }
}

// ---------------------------------------------------------------------------
// Kernel 2: reduce 16 partials + bias + LayerNorm + K/V proj (vector ALU).
// Grid 512 x 256 thr; one wave per kv token. No barriers.
// (Round-0 proven version.)
// ---------------------------------------------------------------------------
__global__ __launch_bounds__(256) void lnkv_kernel(
    const float* __restrict__ partials, const float* __restrict__ bsr,
    const float* __restrict__ gamma, const float* __restrict__ beta,
    const float* __restrict__ Wk, const float* __restrict__ bk,
    const float* __restrict__ Wv, const float* __restrict__ bv,
    u16* __restrict__ kbuf, u16* __restrict__ vTbuf)
{
    const int wave = threadIdx.x >> 6;
    const int c    = threadIdx.x & 63;
    const int token = blockIdx.x * 4 + wave;

    float acc = 0.f;
#pragma unroll
    for (int s = 0; s < 16; ++s)
        acc += partials[(size_t)s * 131072 + (size_t)token * 64 + c];
    acc += bsr[c];

    float sum = acc, sumsq = acc * acc;
#pragma unroll
    for (int m = 1; m < 64; m <<= 1) {
        sum   += __shfl_xor(sum, m, 64);
        sumsq += __shfl_xor(sumsq, m, 64);
    }
    float mean = sum * (1.f / 64.f);
    float var  = sumsq * (1.f / 64.f) - mean * mean;
    float inv  = rsqrtf(var + 1e-5f);
    float xn   = (acc - mean) * inv * gamma[c] + beta[c];

    __shared__ float sxn[4][64];
    sxn[wave][c] = xn;

    float ka = bk[c], va = bv[c];
#pragma unroll 8
    for (int ci = 0; ci < 64; ++ci) {
        float xv = sxn[wave][ci];
        ka += xv * Wk[ci * 64 + c];
        va += xv * Wv[ci * 64 + c];
    }
    kbuf[(size_t)token * 64 + c] = f2bf(ka);
    int b = token >> 8, t = token & 255;
    vTbuf[(size_t)b * 16384 + c * 256 + t] = f2bf(va);
}

// ---------------------------------------------------------------------------
// Kernel 3: fused q-proj + attention + out-proj, all-transposed chain.
// (Round-1 PROVEN version, verbatim: 512 blocks x 512 thr, joint 2-qt
// chain, sWq/sWp in LDS, x loads hoisted above the staging barrier.
// Ran <= 42 us in rounds 1 and 3 — accumulators live in AGPRs. Do not
// "improve" this kernel again without per-kernel counter evidence.)
// ---------------------------------------------------------------------------
__global__ __launch_bounds__(512) void attn_kernel(
    const float* __restrict__ x, const u16* __restrict__ WqT,
    const float* __restrict__ bq, const u16* __restrict__ WpT,
    const float* __restrict__ bp, const u16* __restrict__ kbuf,
    const u16* __restrict__ vTbuf, float* __restrict__ out)
{
    const int batch = blockIdx.x >> 6;
    const int row0  = (blockIdx.x & 63) * 256;
    const int tid  = threadIdx.x;
    const int wave = tid >> 6;
    const int lane = tid & 63;
    const int l15  = lane & 15;
    const int quad = lane >> 4;

    __shared__ u16 sK[256 * 72];      // k[token][d]      36.0 KB
    __shared__ u16 sV[64 * 264];      // vT[d][token]     33.8 KB
    __shared__ u16 sWq[64 * 72];      // Wq^T [co][ci]     9.0 KB
    __shared__ u16 sWp[64 * 72];      // Wp^T [co][ci]     9.0 KB

    const int qbase = row0 + wave * 32;   // this wave's 32 q-rows

    // ---- hoisted q-proj x loads: issue BEFORE staging, consume after barrier
    f4 xq[4][2];
#pragma unroll
    for (int kt = 0; kt < 4; ++kt)
#pragma unroll
        for (int qt = 0; qt < 2; ++qt)
            xq[kt][qt] = *(const f4*)(x + ((size_t)(batch * 16384 + qbase + qt * 16 + l15)) * 64 + kt * 16 + quad * 4);

    // ---- staging (only barrier in the kernel) ----
#pragma unroll
    for (int p = 0; p < 4; ++p) {
        int idx = p * 512 + tid; int tt = idx >> 3, seg = idx & 7;
        *(short8*)&sK[tt * 72 + seg * 8] =
            *(const short8*)(kbuf + ((size_t)(batch * 256 + tt)) * 64 + seg * 8);
    }
#pragma unroll
    for (int p = 0; p < 4; ++p) {
        int idx = p * 512 + tid; int d = idx >> 5, seg = idx & 31;
        *(short8*)&sV[d * 264 + seg * 8] =
            *(const short8*)(vTbuf + ((size_t)(batch * 64 + d)) * 256 + seg * 8);
    }
    {
        int co = tid >> 3, g = (tid & 7) * 8;
        *(short8*)&sWq[co * 72 + g] = *(const short8*)(WqT + (size_t)co * 64 + g);
        *(short8*)&sWp[co * 72 + g] = *(const short8*)(WpT + (size_t)co * 64 + g);
    }
    __syncthreads();

    // ---- q^T = Wq^T @ x^T  (A from sWq; B = hoisted x in registers) ----
    f32x4 qT[2][4];
#pragma unroll
    for (int qt = 0; qt < 2; ++qt)
#pragma unroll
        for (int ct = 0; ct < 4; ++ct) { qT[qt][ct][0]=0.f; qT[qt][ct][1]=0.f; qT[qt][ct][2]=0.f; qT[qt][ct][3]=0.f; }
#pragma unroll
    for (int kt = 0; kt < 4; ++kt) {
        short4v bfr[2];
#pragma unroll
        for (int qt = 0; qt < 2; ++qt) bfr[qt] = pack4(xq[kt][qt]);
#pragma unroll
        for (int ct = 0; ct < 4; ++ct) {
            short4v a = *(const short4v*)&sWq[(ct * 16 + l15) * 72 + kt * 16 + quad * 4];
#pragma unroll
            for (int qt = 0; qt < 2; ++qt) qT[qt][ct] = MFMA1K(a, bfr[qt], qT[qt][ct]);
        }
    }
    // bias + 1/sqrt(64), convert to B-frags for S^T
    short4v qf[2][4];
#pragma unroll
    for (int ct = 0; ct < 4; ++ct) {
        f4 bqv = *(const f4*)(bq + ct * 16 + quad * 4);
#pragma unroll
        for (int qt = 0; qt < 2; ++qt) {
            f4 t;
#pragma unroll
            for (int i = 0; i < 4; ++i) t[i] = (qT[qt][ct][i] + bqv[i]) * 0.125f;
            qf[qt][ct] = pack4(t);
        }
    }

    // ---- S^T = K @ q^T  (A from sK; B = qf in registers) ----
    f32x4 st[2][16];
#pragma unroll
    for (int qt = 0; qt < 2; ++qt)
#pragma unroll
        for (int mt = 0; mt < 16; ++mt) { st[qt][mt][0]=0.f; st[qt][mt][1]=0.f; st[qt][mt][2]=0.f; st[qt][mt][3]=0.f; }
#pragma unroll
    for (int mt = 0; mt < 16; ++mt)
#pragma unroll
        for (int kt = 0; kt < 4; ++kt) {
            short4v a = *(const short4v*)&sK[(mt * 16 + l15) * 72 + kt * 16 + quad * 4];
#pragma unroll
            for (int qt = 0; qt < 2; ++qt) st[qt][mt] = MFMA1K(a, qf[qt][kt], st[qt][mt]);
        }

    // ---- softmax over k (rows of S^T): in-lane 64 + 2 cross-quad shuffles ----
    short4v pf[2][16];
    float linv[2];
#pragma unroll
    for (int qt = 0; qt < 2; ++qt) {
        float mx = -1e30f;
#pragma unroll
        for (int mt = 0; mt < 16; ++mt)
#pragma unroll
            for (int i = 0; i < 4; ++i) mx = fmaxf(mx, st[qt][mt][i]);
        mx = fmaxf(mx, __shfl_xor(mx, 16, 64));
        mx = fmaxf(mx, __shfl_xor(mx, 32, 64));
        float l = 0.f;
#pragma unroll
        for (int mt = 0; mt < 16; ++mt) {
            f4 e;
#pragma unroll
            for (int i = 0; i < 4; ++i) { e[i] = __expf(st[qt][mt][i] - mx); l += e[i]; }
            pf[qt][mt] = pack4(e);
        }
        l += __shfl_xor(l, 16, 64);
        l += __shfl_xor(l, 32, 64);
        linv[qt] = 1.0f / l;
    }

    // ---- O^T = V^T @ P^T  (A from sV; B = pf in registers) ----
    f32x4 ot[2][4];
#pragma unroll
    for (int qt = 0; qt < 2; ++qt)
#pragma unroll
        for (int dt = 0; dt < 4; ++dt) { ot[qt][dt][0]=0.f; ot[qt][dt][1]=0.f; ot[qt][dt][2]=0.f; ot[qt][dt][3]=0.f; }
#pragma unroll
    for (int mt = 0; mt < 16; ++mt)
#pragma unroll
        for (int dt = 0; dt < 4; ++dt) {
            short4v a = *(const short4v*)&sV[(dt * 16 + l15) * 264 + mt * 16 + quad * 4];
#pragma unroll
            for (int qt = 0; qt < 2; ++qt) ot[qt][dt] = MFMA1K(a, pf[qt][mt], ot[qt][dt]);
        }

    // ---- final^T = Wp^T @ (O^T / l)  (A from sWp; B in registers) ----
    short4v of[2][4];
#pragma unroll
    for (int dt = 0; dt < 4; ++dt)
#pragma unroll
        for (int qt = 0; qt < 2; ++qt) {
            f4 t;
#pragma unroll
            for (int i = 0; i < 4; ++i) t[i] = ot[qt][dt][i] * linv[qt];
            of[qt][dt] = pack4(t);
        }
    f32x4 ft[2][4];
#pragma unroll
    for (int qt = 0; qt < 2; ++qt)
#pragma unroll
        for (int ct = 0; ct < 4; ++ct) { ft[qt][ct][0]=0.f; ft[qt][ct][1]=0.f; ft[qt][ct][2]=0.f; ft[qt][ct][3]=0.f; }
#pragma unroll
    for (int kt = 0; kt < 4; ++kt)
#pragma unroll
        for (int ct = 0; ct < 4; ++ct) {
            short4v a = *(const short4v*)&sWp[(ct * 16 + l15) * 72 + kt * 16 + quad * 4];
#pragma unroll
            for (int qt = 0; qt < 2; ++qt) ft[qt][ct] = MFMA1K(a, of[qt][kt], ft[qt][ct]);
        }

    // ---- store: lane holds 4 consecutive channels of one row -> dwordx4 ----
#pragma unroll
    for (int ct = 0; ct < 4; ++ct) {
        f4 bpv = *(const f4*)(bp + ct * 16 + quad * 4);
#pragma unroll
        for (int qt = 0; qt < 2; ++qt) {
            f4 r;
#pragma unroll
            for (int i = 0; i < 4; ++i) r[i] = ft[qt][ct][i] + bpv[i];
            *(f4*)(out + ((size_t)(batch * 16384 + qbase + qt * 16 + l15)) * 64 + ct * 16 + quad * 4) = r;
        }
    }
}

// ---------------------------------------------------------------------------
extern "C" void kernel_launch(void* const* d_in, const int* in_sizes, int n_in,
                              void* d_out, int out_size, void* d_ws, size_t ws_size,
                              hipStream_t stream) {
    const float* x     = (const float*)d_in[0];
    const float* Wq    = (const float*)d_in[1];
    const float* bq    = (const float*)d_in[2];
    const float* Wk    = (const float*)d_in[3];
    const float* bk    = (const float*)d_in[4];
    const float* Wv    = (const float*)d_in[5];
    const float* bv    = (const float*)d_in[6];
    const float* Wsr   = (const float*)d_in[7];
    const float* bsr   = (const float*)d_in[8];
    const float* gamma = (const float*)d_in[9];
    const float* beta  = (const float*)d_in[10];
    const float* Wp    = (const float*)d_in[11];
    const float* bp    = (const float*)d_in[12];

    char* w = (char*)d_ws;
    float* partials = (float*)w;                         // 16*2048*64 f32 = 8.4 MB
    u16* kbuf  = (u16*)(w + 8388608);                    // 256 KB
    u16* vTbuf = (u16*)(w + 8388608 + 262144);           // 256 KB
    u16* WsrT  = (u16*)(w + 8388608 + 524288);           // 512 KB
    u16* WqT   = (u16*)(w + 8388608 + 524288 + 524288);  // 8 KB
    u16* WpT   = (u16*)(w + 8388608 + 524288 + 524288 + 8192);
    float* out = (float*)d_out;

    prep_kernel<<<66, 256, 0, stream>>>(Wsr, Wq, Wp, WsrT, WqT, WpT);
    conv_partial_kernel<<<512, 256, 0, stream>>>(x, WsrT, partials);
    lnkv_kernel<<<512, 256, 0, stream>>>(partials, bsr, gamma, beta, Wk, bk, Wv, bv, kbuf, vTbuf);
    attn_kernel<<<512, 512, 0, stream>>>(x, WqT, bq, WpT, bp, kbuf, vTbuf, out);
}